// Round 1
// baseline (506.432 us; speedup 1.0000x reference)
//
#include <hip/hip_runtime.h>

// HMM forward, log-semiring chunked scan.
// B=8, T=4096, S=64.  C=128 chunks of L=32 steps.
// Phase 1: B*C workgroups each compute the chunk transfer matrix in
//          normalized form (m_row[i], E[i][k] = exp(M - m_row) in (0,1]).
//          Stored to ws TRANSPOSED: wsE[(b*C+c)*4096 + j*64 + i] = E[i][j].
// Phase 2: 8 workgroups (one per batch) sequentially fold the 128 chunk
//          matrices into alpha, then logsumexp -> out[b].

#define HMM_B 8
#define HMM_T 4096
#define HMM_S 64
#define HMM_C 128
#define HMM_L (HMM_T / HMM_C)   // 32
#define FP 68                    // padded LDS row stride (words); 68*4B is 16B-aligned

__global__ __launch_bounds__(256, 3)
void hmm_phase1(const float* __restrict__ lf, float* __restrict__ wsE,
                float* __restrict__ wsM) {
  __shared__ float fS[64 * FP];   // factor tile (then F = exp(f - colmax))
  __shared__ float etA[64 * FP];  // E^T double buffer A  (Et[k][i] = E[i][k])
  __shared__ float etB[64 * FP];  // E^T double buffer B
  __shared__ float colmax[64];
  __shared__ float expc[64];
  __shared__ float mrow[64];

  const int tid = threadIdx.x;
  const int wg  = blockIdx.x;
  const int b   = wg >> 7;            // wg / HMM_C
  const int c   = wg & (HMM_C - 1);
  const float* fbase =
      lf + ((size_t)(b * HMM_T + c * HMM_L)) * (HMM_S * HMM_S);

  const int tx = tid & 15;   // output col tile: j0 = tx*4
  const int ty = tid >> 4;   // output row tile: i0 = ty*4
  const int jj = tid & 63;
  const int p  = tid >> 6;

  // ---- load first factor f_{t0} ----
  {
    const float4* src = (const float4*)fbase;
#pragma unroll
    for (int r = 0; r < 4; ++r) {
      float4 v = src[r * 256 + tid];
      int o = (r * 256 + tid) << 2;            // flat element offset
      *(float4*)&fS[(o >> 6) * FP + (o & 63)] = v;
    }
  }
  __syncthreads();

  // ---- init state: mrow[i] = max_k f0[i][k]; Et[k][i] = exp(f0[i][k]-mrow[i])
  {
    float* redp = etB;  // dead storage right now
    float pm = -3.402823466e38f;
#pragma unroll
    for (int kk = 0; kk < 16; ++kk)
      pm = fmaxf(pm, fS[jj * FP + p * 16 + kk]);   // row jj, contiguous
    redp[p * 64 + jj] = pm;
    __syncthreads();
    if (tid < 64)
      mrow[tid] = fmaxf(fmaxf(redp[tid], redp[64 + tid]),
                        fmaxf(redp[128 + tid], redp[192 + tid]));
    __syncthreads();
    float m = mrow[jj];
#pragma unroll
    for (int kk = 0; kk < 16; ++kk) {
      int k = p * 16 + kk;
      etA[k * FP + jj] = __expf(fS[jj * FP + k] - m);
    }
  }
  __syncthreads();

  float* etCur = etA;
  float* etNxt = etB;

  for (int t = 1; t < HMM_L; ++t) {
    // ---- load f_t ----
    {
      const float4* src = (const float4*)(fbase + (size_t)t * (HMM_S * HMM_S));
#pragma unroll
      for (int r = 0; r < 4; ++r) {
        float4 v = src[r * 256 + tid];
        int o = (r * 256 + tid) << 2;
        *(float4*)&fS[(o >> 6) * FP + (o & 63)] = v;
      }
    }
    __syncthreads();

    // ---- colmax[j] = max_k f[k][j];  expc[j] = exp(colmax[j]) ----
    {
      float* redp = etNxt;  // dead until matmul writes it
      float pm = -3.402823466e38f;
#pragma unroll
      for (int kk = 0; kk < 16; ++kk)
        pm = fmaxf(pm, fS[(p * 16 + kk) * FP + jj]);
      redp[p * 64 + jj] = pm;
      __syncthreads();
      if (tid < 64) {
        float m = fmaxf(fmaxf(redp[tid], redp[64 + tid]),
                        fmaxf(redp[128 + tid], redp[192 + tid]));
        colmax[tid] = m;
        expc[tid]   = __expf(m);
      }
    }
    __syncthreads();

    // ---- F = exp(f - colmax), column-wise ----
    {
      float m = colmax[jj];
#pragma unroll
      for (int kk = 0; kk < 16; ++kk) {
        int k = p * 16 + kk;
        fS[k * FP + jj] = __expf(fS[k * FP + jj] - m);
      }
    }
    __syncthreads();

    // ---- P[i][j] = sum_k E[i][k] * F[k][j]   (4x4 register tile) ----
    float4 acc0 = {0.f, 0.f, 0.f, 0.f};
    float4 acc1 = acc0, acc2 = acc0, acc3 = acc0;
#pragma unroll 8
    for (int k = 0; k < 64; ++k) {
      float4 a  = *(const float4*)&etCur[k * FP + (ty << 2)];  // E[i0..i0+3][k]
      float4 f4 = *(const float4*)&fS[k * FP + (tx << 2)];     // F[k][j0..j0+3]
      acc0.x = fmaf(a.x, f4.x, acc0.x); acc0.y = fmaf(a.x, f4.y, acc0.y);
      acc0.z = fmaf(a.x, f4.z, acc0.z); acc0.w = fmaf(a.x, f4.w, acc0.w);
      acc1.x = fmaf(a.y, f4.x, acc1.x); acc1.y = fmaf(a.y, f4.y, acc1.y);
      acc1.z = fmaf(a.y, f4.z, acc1.z); acc1.w = fmaf(a.y, f4.w, acc1.w);
      acc2.x = fmaf(a.z, f4.x, acc2.x); acc2.y = fmaf(a.z, f4.y, acc2.y);
      acc2.z = fmaf(a.z, f4.z, acc2.z); acc2.w = fmaf(a.z, f4.w, acc2.w);
      acc3.x = fmaf(a.w, f4.x, acc3.x); acc3.y = fmaf(a.w, f4.y, acc3.y);
      acc3.z = fmaf(a.w, f4.z, acc3.z); acc3.w = fmaf(a.w, f4.w, acc3.w);
    }

    // ---- Q = P * expc[j];  nu_i = max_j Q[i][j] (shfl over the 16 tx lanes)
    {
      float e0 = expc[(tx << 2) + 0], e1 = expc[(tx << 2) + 1];
      float e2 = expc[(tx << 2) + 2], e3 = expc[(tx << 2) + 3];
      acc0.x *= e0; acc0.y *= e1; acc0.z *= e2; acc0.w *= e3;
      acc1.x *= e0; acc1.y *= e1; acc1.z *= e2; acc1.w *= e3;
      acc2.x *= e0; acc2.y *= e1; acc2.z *= e2; acc2.w *= e3;
      acc3.x *= e0; acc3.y *= e1; acc3.z *= e2; acc3.w *= e3;

      float rm0 = fmaxf(fmaxf(acc0.x, acc0.y), fmaxf(acc0.z, acc0.w));
      float rm1 = fmaxf(fmaxf(acc1.x, acc1.y), fmaxf(acc1.z, acc1.w));
      float rm2 = fmaxf(fmaxf(acc2.x, acc2.y), fmaxf(acc2.z, acc2.w));
      float rm3 = fmaxf(fmaxf(acc3.x, acc3.y), fmaxf(acc3.z, acc3.w));
#pragma unroll
      for (int off = 1; off < 16; off <<= 1) {
        rm0 = fmaxf(rm0, __shfl_xor(rm0, off));
        rm1 = fmaxf(rm1, __shfl_xor(rm1, off));
        rm2 = fmaxf(rm2, __shfl_xor(rm2, off));
        rm3 = fmaxf(rm3, __shfl_xor(rm3, off));
      }
      float inv0 = 1.0f / rm0, inv1 = 1.0f / rm1;
      float inv2 = 1.0f / rm2, inv3 = 1.0f / rm3;

      // E'[i][j] = Q/nu, stored transposed: etNxt[j][i]
      float4 v;
      v.x = acc0.x * inv0; v.y = acc1.x * inv1; v.z = acc2.x * inv2; v.w = acc3.x * inv3;
      *(float4*)&etNxt[((tx << 2) + 0) * FP + (ty << 2)] = v;
      v.x = acc0.y * inv0; v.y = acc1.y * inv1; v.z = acc2.y * inv2; v.w = acc3.y * inv3;
      *(float4*)&etNxt[((tx << 2) + 1) * FP + (ty << 2)] = v;
      v.x = acc0.z * inv0; v.y = acc1.z * inv1; v.z = acc2.z * inv2; v.w = acc3.z * inv3;
      *(float4*)&etNxt[((tx << 2) + 2) * FP + (ty << 2)] = v;
      v.x = acc0.w * inv0; v.y = acc1.w * inv1; v.z = acc2.w * inv2; v.w = acc3.w * inv3;
      *(float4*)&etNxt[((tx << 2) + 3) * FP + (ty << 2)] = v;

      if (tx == 0) {
        mrow[(ty << 2) + 0] += __logf(rm0);
        mrow[(ty << 2) + 1] += __logf(rm1);
        mrow[(ty << 2) + 2] += __logf(rm2);
        mrow[(ty << 2) + 3] += __logf(rm3);
      }
    }
    { float* tmp = etCur; etCur = etNxt; etNxt = tmp; }
    __syncthreads();
  }

  // ---- write out chunk result: wsE[(b*C+c)*4096 + j*64 + i] = E[i][j] ----
  {
    float* dst = wsE + ((size_t)(b * HMM_C + c) << 12) + jj * 64 + p * 16;
#pragma unroll
    for (int q4 = 0; q4 < 4; ++q4) {
      float4 v = *(const float4*)&etCur[jj * FP + p * 16 + (q4 << 2)];
      *(float4*)(dst + (q4 << 2)) = v;
    }
    if (tid < 64) wsM[((b * HMM_C + c) << 6) + tid] = mrow[tid];
  }
}

__global__ __launch_bounds__(256)
void hmm_phase2(const float* __restrict__ wsE, const float* __restrict__ wsM,
                const float* __restrict__ linit, float* __restrict__ out) {
  __shared__ float wS[64];
  __shared__ float red[4][64];
  __shared__ float mS;

  const int tid = threadIdx.x;
  const int b   = blockIdx.x;
  const int j   = tid & 63;
  const int p   = tid >> 6;

  float alphaR = 0.0f;                 // lane i (wave 0) holds alpha[i]
  if (tid < 64) alphaR = linit[b * 64 + tid];

  for (int c = 0; c < HMM_C; ++c) {
    const float* Eg = wsE + ((size_t)(b * HMM_C + c) << 12);
    if (tid < 64) {
      float bi = alphaR + wsM[((b * HMM_C + c) << 6) + tid];
      float m = bi;
#pragma unroll
      for (int off = 32; off > 0; off >>= 1) m = fmaxf(m, __shfl_xor(m, off));
      wS[tid] = __expf(bi - m);
      if (tid == 0) mS = m;
    }
    __syncthreads();
    // s[j] = sum_i w[i] * E[i][j];  E stored transposed: Eg[j*64 + i]
    float sp = 0.0f;
#pragma unroll
    for (int q4 = 0; q4 < 4; ++q4) {
      float4 e4 = *(const float4*)&Eg[j * 64 + p * 16 + (q4 << 2)];
      int i0 = p * 16 + (q4 << 2);
      sp = fmaf(wS[i0 + 0], e4.x, sp);
      sp = fmaf(wS[i0 + 1], e4.y, sp);
      sp = fmaf(wS[i0 + 2], e4.z, sp);
      sp = fmaf(wS[i0 + 3], e4.w, sp);
    }
    red[p][j] = sp;
    __syncthreads();
    if (tid < 64) {
      float s = red[0][tid] + red[1][tid] + red[2][tid] + red[3][tid];
      alphaR = mS + __logf(s);
    }
  }

  if (tid < 64) {
    float m = alphaR;
#pragma unroll
    for (int off = 32; off > 0; off >>= 1) m = fmaxf(m, __shfl_xor(m, off));
    float s = __expf(alphaR - m);
#pragma unroll
    for (int off = 32; off > 0; off >>= 1) s += __shfl_xor(s, off);
    if (tid == 0) out[b] = m + __logf(s);
  }
}

extern "C" void kernel_launch(void* const* d_in, const int* in_sizes, int n_in,
                              void* d_out, int out_size, void* d_ws, size_t ws_size,
                              hipStream_t stream) {
  const float* lf    = (const float*)d_in[0];  // [B,T,S,S] fp32
  const float* linit = (const float*)d_in[1];  // [B,S] fp32
  float* out = (float*)d_out;                  // [B] fp32

  // workspace: E matrices (B*C*64*64 fp32) then m_row (B*C*64 fp32) ~ 16.3 MB
  float* wsE = (float*)d_ws;
  float* wsM = wsE + (size_t)HMM_B * HMM_C * HMM_S * HMM_S;

  hmm_phase1<<<dim3(HMM_B * HMM_C), dim3(256), 0, stream>>>(lf, wsE, wsM);
  hmm_phase2<<<dim3(HMM_B), dim3(256), 0, stream>>>(wsE, wsM, linit, out);
}

// Round 2
// 265.746 us; speedup vs baseline: 1.9057x; 1.9057x over previous
//
#include <hip/hip_runtime.h>

// HMM forward, log-semiring chunked scan, MFMA edition.
// B=8, T=4096, S=64.  C=128 chunks of L=32 steps.
// Phase 1 (1024 WGs, 256 thr): chunk transfer matrix via bf16 MFMA.
//   State E (row-normalized, rowmax=1) kept as bf16; per-step:
//     stage f_t (fp32, global_load_lds w/ XOR-swizzled source),
//     F = exp(f_t) transposed+packed to B-frag-linear LDS,
//     P = E*F via 8x mfma_f32_16x16x32_bf16 per wave,
//     rowmax (DPP reduce), E' = P/rowmax, mrow += log2(rowmax).
//   Output: wsEt[(b*128+c)][j][i] = E[i][j] (bf16), wsM = mrow*ln2 (f32).
// Phase 2 (8 WGs, 64 thr): fold 128 chunks into alpha (per-lane), depth-4
//   register prefetch, readlane broadcast matvec; logsumexp -> out[b].

#define HMM_B 8
#define HMM_T 4096
#define HMM_S 64
#define HMM_C 128
#define HMM_L (HMM_T / HMM_C)   // 32

typedef __attribute__((ext_vector_type(8))) short s16x8;
typedef __attribute__((ext_vector_type(4))) float f32x4;
typedef __attribute__((ext_vector_type(4))) unsigned int u32x4;

__device__ inline void gld16(const float* g, const float* l) {
  __builtin_amdgcn_global_load_lds((const __attribute__((address_space(1))) void*)g,
                                   (__attribute__((address_space(3))) void*)l, 16, 0, 0);
}

__device__ inline unsigned cvtpk(float lo, float hi) {
  unsigned r;
  asm("v_cvt_pk_bf16_f32 %0, %1, %2" : "=v"(r) : "v"(lo), "v"(hi));
  return r;
}

__device__ inline float dpp_fmax16(float x) {
  // max across each 16-lane row: quad_perm xor1, xor2, half_mirror, mirror
  int xi = __float_as_int(x);
  x = fmaxf(x, __int_as_float(__builtin_amdgcn_mov_dpp(xi, 0xB1, 0xF, 0xF, 1)));
  xi = __float_as_int(x);
  x = fmaxf(x, __int_as_float(__builtin_amdgcn_mov_dpp(xi, 0x4E, 0xF, 0xF, 1)));
  xi = __float_as_int(x);
  x = fmaxf(x, __int_as_float(__builtin_amdgcn_mov_dpp(xi, 0x141, 0xF, 0xF, 1)));
  xi = __float_as_int(x);
  x = fmaxf(x, __int_as_float(__builtin_amdgcn_mov_dpp(xi, 0x140, 0xF, 0xF, 1)));
  return x;
}

__global__ __launch_bounds__(256, 2)
void hmm_phase1(const float* __restrict__ lf, unsigned short* __restrict__ wsEt,
                float* __restrict__ wsM) {
  // LDS: 60416 B total -> 2 WGs/CU.
  __shared__ struct {
    float fbuf[2][4096];            // f tile, 16B-slot XOR-swizzled within rows
    unsigned short fB[2][4096];     // F bf16, B-frag-linear slots
    unsigned short escr[4][1408];   // per-wave E rows, stride 88 ushorts (176B)
  } sm;

  const int tid = threadIdx.x;
  const int w   = tid >> 6;     // wave id 0..3 -> output rows 16w..16w+15
  const int l   = tid & 63;     // lane
  const int wg  = blockIdx.x;
  const int bb  = wg >> 7;
  const int cc  = wg & (HMM_C - 1);
  const float* fbase = lf + ((size_t)(bb * HMM_T + cc * HMM_L)) * (HMM_S * HMM_S);

  // ---- issue global_load_lds for step t (4 calls per wave, rows 16w..16w+15)
  auto issue = [&](int t) {
    const int par = t & 1;
    const float* fb = fbase + (size_t)t * 4096;
#pragma unroll
    for (int u = 0; u < 4; ++u) {
      int slot = (w * 4 + u) * 64 + l;        // 16B slot index
      int k    = slot >> 4;                   // row of f
      int q16  = slot & 15;                   // swizzled slot-in-row
      const float* src = fb + k * 64 + ((q16 ^ (k & 7)) << 2);
      gld16(src, &sm.fbuf[par][(w * 4 + u) * 256]);
    }
  };

  issue(0);

  float mracc0 = 0.f, mracc1 = 0.f, mracc2 = 0.f, mracc3 = 0.f;
  const int c4 = l & 15, q = l >> 4;

  for (int t = 0; t < HMM_L; ++t) {
    const int par = t & 1;
    if (t + 1 < HMM_L) issue(t + 1);

    if (t < HMM_L - 1) asm volatile("s_waitcnt vmcnt(4)" ::: "memory");
    else               asm volatile("s_waitcnt vmcnt(0)" ::: "memory");
    __builtin_amdgcn_sched_barrier(0);

    // ---- exp + transpose + pack: my wave's 16 rows -> fB (B-frag-linear)
#pragma unroll
    for (int u = 0; u < 2; ++u) {
      const int g = 2 * w + (l >> 5);         // k-octet index (within my band)
      const int j = (l & 31) + 32 * u;        // column of f
      float v[8];
#pragma unroll
      for (int e = 0; e < 8; ++e) {
        int k = 8 * g + e;
        v[e] = sm.fbuf[par][k * 64 + (((j >> 2) ^ (k & 7)) << 2) + (j & 3)];
      }
      unsigned p0 = cvtpk(__expf(v[0]), __expf(v[1]));
      unsigned p1 = cvtpk(__expf(v[2]), __expf(v[3]));
      unsigned p2 = cvtpk(__expf(v[4]), __expf(v[5]));
      unsigned p3 = cvtpk(__expf(v[6]), __expf(v[7]));
      int slot = ((g >> 2) * 4 + (j >> 4)) * 64 + ((g & 3) << 4) + (j & 15);
      u32x4 o; o.x = p0; o.y = p1; o.z = p2; o.w = p3;
      *(u32x4*)&sm.fB[par][slot * 8] = o;
    }

    asm volatile("s_waitcnt lgkmcnt(0)" ::: "memory");
    __builtin_amdgcn_sched_barrier(0);
    __builtin_amdgcn_s_barrier();

    // ---- A fragments (my E rows; identity at t=0)
    s16x8 a0, a1;
    if (t == 0) {
      const int iloc = 16 * w + (l & 15);
      const int kb0 = (l >> 4) * 8, kb1 = 32 + (l >> 4) * 8;
#pragma unroll
      for (int e = 0; e < 8; ++e) {
        a0[e] = (short)((kb0 + e == iloc) ? 0x3F80 : 0);
        a1[e] = (short)((kb1 + e == iloc) ? 0x3F80 : 0);
      }
    } else {
      a0 = *(const s16x8*)&sm.escr[w][(l & 15) * 88 + ((l >> 4) * 8)];
      a1 = *(const s16x8*)&sm.escr[w][(l & 15) * 88 + 32 + ((l >> 4) * 8)];
    }

    // ---- P = E*F : 4 col-tiles x (K=64 as 2 mfma)
    f32x4 acc[4];
#pragma unroll
    for (int n = 0; n < 4; ++n) {
      s16x8 b0 = *(const s16x8*)&sm.fB[par][((0 + n) * 64 + l) * 8];
      s16x8 b1 = *(const s16x8*)&sm.fB[par][((4 + n) * 64 + l) * 8];
      f32x4 c = {0.f, 0.f, 0.f, 0.f};
      c = __builtin_amdgcn_mfma_f32_16x16x32_bf16(a0, b0, c, 0, 0, 0);
      c = __builtin_amdgcn_mfma_f32_16x16x32_bf16(a1, b1, c, 0, 0, 0);
      acc[n] = c;
    }

    // ---- epilogue: rowmax (over 64 cols), rescale, log-accumulate, store E'
    float inv[4];
    {
      float m0 = fmaxf(fmaxf(acc[0][0], acc[1][0]), fmaxf(acc[2][0], acc[3][0]));
      float m1 = fmaxf(fmaxf(acc[0][1], acc[1][1]), fmaxf(acc[2][1], acc[3][1]));
      float m2 = fmaxf(fmaxf(acc[0][2], acc[1][2]), fmaxf(acc[2][2], acc[3][2]));
      float m3 = fmaxf(fmaxf(acc[0][3], acc[1][3]), fmaxf(acc[2][3], acc[3][3]));
      m0 = dpp_fmax16(m0); m1 = dpp_fmax16(m1);
      m2 = dpp_fmax16(m2); m3 = dpp_fmax16(m3);
      mracc0 += __log2f(m0); mracc1 += __log2f(m1);
      mracc2 += __log2f(m2); mracc3 += __log2f(m3);
      inv[0] = __builtin_amdgcn_rcpf(m0); inv[1] = __builtin_amdgcn_rcpf(m1);
      inv[2] = __builtin_amdgcn_rcpf(m2); inv[3] = __builtin_amdgcn_rcpf(m3);
    }
#pragma unroll
    for (int n = 0; n < 4; ++n) {
      unsigned p0 = cvtpk(acc[n][0] * inv[0], acc[n][1] * inv[1]);
      unsigned p1 = cvtpk(acc[n][2] * inv[2], acc[n][3] * inv[3]);
      sm.escr[w][(4 * q + 0) * 88 + 16 * n + c4] = (unsigned short)(p0 & 0xffffu);
      sm.escr[w][(4 * q + 1) * 88 + 16 * n + c4] = (unsigned short)(p0 >> 16);
      sm.escr[w][(4 * q + 2) * 88 + 16 * n + c4] = (unsigned short)(p1 & 0xffffu);
      sm.escr[w][(4 * q + 3) * 88 + 16 * n + c4] = (unsigned short)(p1 >> 16);
    }
  }

  __syncthreads();

  // ---- write chunk result: wsEt[chunk][j][i] = E[i][j] (bf16), coalesced-ish
  {
    const int j = tid & 63, p4 = tid >> 6;
    const size_t cb = ((size_t)(bb * HMM_C + cc)) * 4096;  // ushort elems
    unsigned short o0[8], o1[8];
#pragma unroll
    for (int rl = 0; rl < 8; ++rl)  o0[rl] = sm.escr[p4][rl * 88 + j];
#pragma unroll
    for (int rl = 0; rl < 8; ++rl)  o1[rl] = sm.escr[p4][(rl + 8) * 88 + j];
    *(u32x4*)&wsEt[cb + j * 64 + p4 * 16]     = *(u32x4*)o0;
    *(u32x4*)&wsEt[cb + j * 64 + p4 * 16 + 8] = *(u32x4*)o1;

    if (c4 == 0) {
      const float ln2 = 0.6931471805599453f;
      float* dst = wsM + (size_t)(bb * HMM_C + cc) * 64 + 16 * w + 4 * q;
      dst[0] = mracc0 * ln2; dst[1] = mracc1 * ln2;
      dst[2] = mracc2 * ln2; dst[3] = mracc3 * ln2;
    }
  }
}

// ---------------- Phase 2 ----------------

__device__ inline float rdlane(float v, int t) {
  return __int_as_float(__builtin_amdgcn_readlane(__float_as_int(v), t));
}
__device__ inline float bflo(int w) { return __uint_as_float(((unsigned)w) << 16); }
__device__ inline float bfhi(int w) { return __uint_as_float(((unsigned)w) & 0xffff0000u); }

__global__ __launch_bounds__(64)
void hmm_phase2(const unsigned short* __restrict__ wsEt, const float* __restrict__ wsM,
                const float* __restrict__ linit, float* __restrict__ out) {
  const int b = blockIdx.x;
  const int jl = threadIdx.x;   // lane = state index

  float alpha = linit[b * 64 + jl];

  int4 eA[8], eB[8], eC[8], eD[8];
  float mA, mB, mC, mD;

#define PLOAD(ES, MS, c) {                                                       \
    const int4* _s = (const int4*)(wsEt + ((size_t)(b * HMM_C + (c))) * 4096 +   \
                                   (size_t)jl * 64);                             \
    _Pragma("unroll") for (int u = 0; u < 8; ++u) ES[u] = _s[u];                 \
    MS = wsM[(size_t)(b * HMM_C + (c)) * 64 + jl];                               \
  }

#define PBODY(ES, MS) {                                                          \
    float av = alpha + MS;                                                       \
    float mx = av;                                                               \
    mx = fmaxf(mx, __shfl_xor(mx, 1));  mx = fmaxf(mx, __shfl_xor(mx, 2));       \
    mx = fmaxf(mx, __shfl_xor(mx, 4));  mx = fmaxf(mx, __shfl_xor(mx, 8));       \
    mx = fmaxf(mx, __shfl_xor(mx, 16)); mx = fmaxf(mx, __shfl_xor(mx, 32));      \
    float wv = __expf(av - mx);                                                  \
    float s = 0.f;                                                               \
    _Pragma("unroll") for (int u = 0; u < 8; ++u) {                              \
      int w0 = ES[u].x, w1 = ES[u].y, w2 = ES[u].z, w3 = ES[u].w;                \
      s = fmaf(rdlane(wv, 8 * u + 0), bflo(w0), s);                              \
      s = fmaf(rdlane(wv, 8 * u + 1), bfhi(w0), s);                              \
      s = fmaf(rdlane(wv, 8 * u + 2), bflo(w1), s);                              \
      s = fmaf(rdlane(wv, 8 * u + 3), bfhi(w1), s);                              \
      s = fmaf(rdlane(wv, 8 * u + 4), bflo(w2), s);                              \
      s = fmaf(rdlane(wv, 8 * u + 5), bfhi(w2), s);                              \
      s = fmaf(rdlane(wv, 8 * u + 6), bflo(w3), s);                              \
      s = fmaf(rdlane(wv, 8 * u + 7), bfhi(w3), s);                              \
    }                                                                            \
    alpha = mx + __logf(s);                                                      \
  }

  PLOAD(eA, mA, 0); PLOAD(eB, mB, 1); PLOAD(eC, mC, 2); PLOAD(eD, mD, 3);

  for (int c0 = 0; c0 < HMM_C; c0 += 4) {
    PBODY(eA, mA); if (c0 + 4 < HMM_C) PLOAD(eA, mA, c0 + 4);
    PBODY(eB, mB); if (c0 + 5 < HMM_C) PLOAD(eB, mB, c0 + 5);
    PBODY(eC, mC); if (c0 + 6 < HMM_C) PLOAD(eC, mC, c0 + 6);
    PBODY(eD, mD); if (c0 + 7 < HMM_C) PLOAD(eD, mD, c0 + 7);
  }

  // final logsumexp over lanes
  float mx = alpha;
  mx = fmaxf(mx, __shfl_xor(mx, 1));  mx = fmaxf(mx, __shfl_xor(mx, 2));
  mx = fmaxf(mx, __shfl_xor(mx, 4));  mx = fmaxf(mx, __shfl_xor(mx, 8));
  mx = fmaxf(mx, __shfl_xor(mx, 16)); mx = fmaxf(mx, __shfl_xor(mx, 32));
  float s = __expf(alpha - mx);
  s += __shfl_xor(s, 1);  s += __shfl_xor(s, 2);  s += __shfl_xor(s, 4);
  s += __shfl_xor(s, 8);  s += __shfl_xor(s, 16); s += __shfl_xor(s, 32);
  if (jl == 0) out[b] = mx + __logf(s);
}

extern "C" void kernel_launch(void* const* d_in, const int* in_sizes, int n_in,
                              void* d_out, int out_size, void* d_ws, size_t ws_size,
                              hipStream_t stream) {
  (void)in_sizes; (void)n_in; (void)out_size; (void)ws_size;
  const float* lf    = (const float*)d_in[0];  // [B,T,S,S] fp32
  const float* linit = (const float*)d_in[1];  // [B,S] fp32
  float* out = (float*)d_out;                  // [B] fp32

  unsigned short* wsEt = (unsigned short*)d_ws;                 // 8 MB bf16 E^T
  float* wsM = (float*)(wsEt + (size_t)HMM_B * HMM_C * 4096);   // 256 KB f32

  hmm_phase1<<<dim3(HMM_B * HMM_C), dim3(256), 0, stream>>>(lf, wsEt, wsM);
  hmm_phase2<<<dim3(HMM_B), dim3(64), 0, stream>>>(wsEt, wsM, linit, out);
}

// Round 3
// 208.215 us; speedup vs baseline: 2.4323x; 1.2763x over previous
//
#include <hip/hip_runtime.h>

// HMM forward, log-semiring chunked scan, MFMA + tree-combine edition.
// B=8, T=4096, S=64.  C=128 chunks of L=32 steps.
// Phase 1 (1024 WGs, 256 thr, 3 WGs/CU): chunk transfer matrix via bf16 MFMA.
//   Emits E row-major (A-side), E^T (B-side), and row-log m (f32).
// Tree (7 launches): pairwise combine chunk matrices with MFMA.
// Final (8 WGs): fold log_init into the per-batch root matrix -> out[b].

#define HMM_B 8
#define HMM_T 4096
#define HMM_S 64
#define HMM_C 128
#define HMM_L (HMM_T / HMM_C)   // 32

typedef __attribute__((ext_vector_type(8))) short s16x8;
typedef __attribute__((ext_vector_type(4))) float f32x4;
typedef __attribute__((ext_vector_type(4))) unsigned int u32x4;

__device__ inline void gld16(const float* g, const float* l) {
  __builtin_amdgcn_global_load_lds((const __attribute__((address_space(1))) void*)g,
                                   (__attribute__((address_space(3))) void*)l, 16, 0, 0);
}

__device__ inline unsigned cvtpk(float lo, float hi) {
  unsigned r;
  asm("v_cvt_pk_bf16_f32 %0, %1, %2" : "=v"(r) : "v"(lo), "v"(hi));
  return r;
}

__device__ inline float dpp_fmax16(float x) {
  int xi = __float_as_int(x);
  x = fmaxf(x, __int_as_float(__builtin_amdgcn_mov_dpp(xi, 0xB1, 0xF, 0xF, 1)));
  xi = __float_as_int(x);
  x = fmaxf(x, __int_as_float(__builtin_amdgcn_mov_dpp(xi, 0x4E, 0xF, 0xF, 1)));
  xi = __float_as_int(x);
  x = fmaxf(x, __int_as_float(__builtin_amdgcn_mov_dpp(xi, 0x141, 0xF, 0xF, 1)));
  xi = __float_as_int(x);
  x = fmaxf(x, __int_as_float(__builtin_amdgcn_mov_dpp(xi, 0x140, 0xF, 0xF, 1)));
  return x;
}

__device__ inline float bflo(unsigned w) { return __uint_as_float(w << 16); }
__device__ inline float bfhi(unsigned w) { return __uint_as_float(w & 0xffff0000u); }

// ---------------- Phase 1 ----------------

__global__ __launch_bounds__(256, 3)
void hmm_phase1(const float* __restrict__ lf, unsigned short* __restrict__ wsE,
                unsigned short* __restrict__ wsEt, float* __restrict__ wsM) {
  // LDS: 52224 B -> 3 WGs/CU.
  __shared__ struct {
    float fbuf[2][4096];            // f tile, 16B-slot XOR-swizzled within rows
    unsigned short fB[4096];        // F bf16, B-frag-linear slots (single buf)
    unsigned short escr[4][1408];   // per-wave E rows, stride 88 ushorts (176B)
  } sm;

  const int tid = threadIdx.x;
  const int w   = tid >> 6;     // wave id 0..3 -> output rows 16w..16w+15
  const int l   = tid & 63;     // lane
  const int wg  = blockIdx.x;
  const int bb  = wg >> 7;
  const int cc  = wg & (HMM_C - 1);
  const float* fbase = lf + ((size_t)(bb * HMM_T + cc * HMM_L)) * (HMM_S * HMM_S);

  auto issue = [&](int t) {
    const int par = t & 1;
    const float* fb = fbase + (size_t)t * 4096;
#pragma unroll
    for (int u = 0; u < 4; ++u) {
      int slot = (w * 4 + u) * 64 + l;        // 16B slot index
      int k    = slot >> 4;                   // row of f
      int q16  = slot & 15;                   // swizzled slot-in-row
      const float* src = fb + k * 64 + ((q16 ^ (k & 7)) << 2);
      gld16(src, &sm.fbuf[par][(w * 4 + u) * 256]);
    }
  };

  issue(0);

  float mracc0 = 0.f, mracc1 = 0.f, mracc2 = 0.f, mracc3 = 0.f;
  const int c4 = l & 15, q = l >> 4;

  for (int t = 0; t < HMM_L; ++t) {
    const int par = t & 1;
    if (t + 1 < HMM_L) issue(t + 1);

    if (t < HMM_L - 1) asm volatile("s_waitcnt vmcnt(4)" ::: "memory");
    else               asm volatile("s_waitcnt vmcnt(0)" ::: "memory");
    __builtin_amdgcn_sched_barrier(0);

    // ---- exp + transpose + pack: my wave's 16 rows -> fB (B-frag-linear)
#pragma unroll
    for (int u = 0; u < 2; ++u) {
      const int g = 2 * w + (l >> 5);         // k-octet index (within my band)
      const int j = (l & 31) + 32 * u;        // column of f
      float v[8];
#pragma unroll
      for (int e = 0; e < 8; ++e) {
        int k = 8 * g + e;
        v[e] = sm.fbuf[par][k * 64 + (((j >> 2) ^ (k & 7)) << 2) + (j & 3)];
      }
      unsigned p0 = cvtpk(__expf(v[0]), __expf(v[1]));
      unsigned p1 = cvtpk(__expf(v[2]), __expf(v[3]));
      unsigned p2 = cvtpk(__expf(v[4]), __expf(v[5]));
      unsigned p3 = cvtpk(__expf(v[6]), __expf(v[7]));
      int slot = ((g >> 2) * 4 + (j >> 4)) * 64 + ((g & 3) << 4) + (j & 15);
      u32x4 o; o.x = p0; o.y = p1; o.z = p2; o.w = p3;
      *(u32x4*)&sm.fB[slot * 8] = o;
    }

    asm volatile("s_waitcnt lgkmcnt(0)" ::: "memory");
    __builtin_amdgcn_sched_barrier(0);
    __builtin_amdgcn_s_barrier();

    // ---- A fragments (my E rows; identity at t=0)
    s16x8 a0, a1;
    if (t == 0) {
      const int iloc = 16 * w + (l & 15);
      const int kb0 = (l >> 4) * 8, kb1 = 32 + (l >> 4) * 8;
#pragma unroll
      for (int e = 0; e < 8; ++e) {
        a0[e] = (short)((kb0 + e == iloc) ? 0x3F80 : 0);
        a1[e] = (short)((kb1 + e == iloc) ? 0x3F80 : 0);
      }
    } else {
      a0 = *(const s16x8*)&sm.escr[w][(l & 15) * 88 + ((l >> 4) * 8)];
      a1 = *(const s16x8*)&sm.escr[w][(l & 15) * 88 + 32 + ((l >> 4) * 8)];
    }

    // ---- P = E*F : 4 col-tiles x (K=64 as 2 mfma)
    f32x4 acc[4];
#pragma unroll
    for (int n = 0; n < 4; ++n) {
      s16x8 b0 = *(const s16x8*)&sm.fB[((0 + n) * 64 + l) * 8];
      s16x8 b1 = *(const s16x8*)&sm.fB[((4 + n) * 64 + l) * 8];
      f32x4 c = {0.f, 0.f, 0.f, 0.f};
      c = __builtin_amdgcn_mfma_f32_16x16x32_bf16(a0, b0, c, 0, 0, 0);
      c = __builtin_amdgcn_mfma_f32_16x16x32_bf16(a1, b1, c, 0, 0, 0);
      acc[n] = c;
    }

    // ---- epilogue: rowmax, rescale, log-accumulate, store E'
    float inv[4];
    {
      float m0 = fmaxf(fmaxf(acc[0][0], acc[1][0]), fmaxf(acc[2][0], acc[3][0]));
      float m1 = fmaxf(fmaxf(acc[0][1], acc[1][1]), fmaxf(acc[2][1], acc[3][1]));
      float m2 = fmaxf(fmaxf(acc[0][2], acc[1][2]), fmaxf(acc[2][2], acc[3][2]));
      float m3 = fmaxf(fmaxf(acc[0][3], acc[1][3]), fmaxf(acc[2][3], acc[3][3]));
      m0 = dpp_fmax16(m0); m1 = dpp_fmax16(m1);
      m2 = dpp_fmax16(m2); m3 = dpp_fmax16(m3);
      mracc0 += __log2f(m0); mracc1 += __log2f(m1);
      mracc2 += __log2f(m2); mracc3 += __log2f(m3);
      inv[0] = __builtin_amdgcn_rcpf(m0); inv[1] = __builtin_amdgcn_rcpf(m1);
      inv[2] = __builtin_amdgcn_rcpf(m2); inv[3] = __builtin_amdgcn_rcpf(m3);
    }
#pragma unroll
    for (int n = 0; n < 4; ++n) {
      unsigned p0 = cvtpk(acc[n][0] * inv[0], acc[n][1] * inv[1]);
      unsigned p1 = cvtpk(acc[n][2] * inv[2], acc[n][3] * inv[3]);
      sm.escr[w][(4 * q + 0) * 88 + 16 * n + c4] = (unsigned short)(p0 & 0xffffu);
      sm.escr[w][(4 * q + 1) * 88 + 16 * n + c4] = (unsigned short)(p0 >> 16);
      sm.escr[w][(4 * q + 2) * 88 + 16 * n + c4] = (unsigned short)(p1 & 0xffffu);
      sm.escr[w][(4 * q + 3) * 88 + 16 * n + c4] = (unsigned short)(p1 >> 16);
    }
    __syncthreads();   // protect single fB buffer for next step's writes
  }

  // ---- write chunk results
  {
    const size_t cb = ((size_t)(bb * HMM_C + cc)) * 4096;  // ushort elems
    // E^T: wsEt[cb + j*64 + i]
    const int j = tid & 63, p4 = tid >> 6;
    unsigned short o0[8], o1[8];
#pragma unroll
    for (int rl = 0; rl < 8; ++rl)  o0[rl] = sm.escr[p4][rl * 88 + j];
#pragma unroll
    for (int rl = 0; rl < 8; ++rl)  o1[rl] = sm.escr[p4][(rl + 8) * 88 + j];
    *(u32x4*)&wsEt[cb + j * 64 + p4 * 16]     = *(u32x4*)o0;
    *(u32x4*)&wsEt[cb + j * 64 + p4 * 16 + 8] = *(u32x4*)o1;

    // E row-major: wsE[cb + i*64 + j]
    const int r = tid >> 2, jq = tid & 3;
    u32x4 v0 = *(const u32x4*)&sm.escr[r >> 4][(r & 15) * 88 + jq * 16];
    u32x4 v1 = *(const u32x4*)&sm.escr[r >> 4][(r & 15) * 88 + jq * 16 + 8];
    *(u32x4*)&wsE[cb + r * 64 + jq * 16]     = v0;
    *(u32x4*)&wsE[cb + r * 64 + jq * 16 + 8] = v1;

    if (c4 == 0) {
      const float ln2 = 0.6931471805599453f;
      float* dst = wsM + (size_t)(bb * HMM_C + cc) * 64 + 16 * w + 4 * q;
      dst[0] = mracc0 * ln2; dst[1] = mracc1 * ln2;
      dst[2] = mracc2 * ln2; dst[3] = mracc3 * ln2;
    }
  }
}

// ---------------- Tree combine ----------------
// out(p) = in(2p) . in(2p+1):  P = E1 * diag(exp(m2-mu)) * E2,
// row-normalized; m_out[i] = m1[i] + mu + log(rowmax_i).

__global__ __launch_bounds__(64)
void hmm_combine(const unsigned short* __restrict__ inE,
                 const unsigned short* __restrict__ inEt,
                 const float* __restrict__ inM, int inBS,
                 unsigned short* __restrict__ outE,
                 unsigned short* __restrict__ outEt,
                 float* __restrict__ outM, int outBS, int nOut) {
  __shared__ float sS[64];
  __shared__ float sM1[64];
  const int l = threadIdx.x, c4 = l & 15, q = l >> 4;
  const int b = blockIdx.x / nOut, p = blockIdx.x % nOut;
  const size_t li = (size_t)(b * inBS + 2 * p) * 4096;
  const size_t ri = li + 4096;
  const float* m1p = inM + (size_t)(b * inBS + 2 * p) * 64;

  float m2v = m1p[64 + l];
  float m1v = m1p[l];
  float mu = m2v;
  mu = fmaxf(mu, __shfl_xor(mu, 1));  mu = fmaxf(mu, __shfl_xor(mu, 2));
  mu = fmaxf(mu, __shfl_xor(mu, 4));  mu = fmaxf(mu, __shfl_xor(mu, 8));
  mu = fmaxf(mu, __shfl_xor(mu, 16)); mu = fmaxf(mu, __shfl_xor(mu, 32));
  sS[l] = __expf(m2v - mu);
  sM1[l] = m1v;
  __syncthreads();

  // A fragments from left child, row-major
  const unsigned short* E1 = inE + li;
  s16x8 afr[4][2];
#pragma unroll
  for (int m = 0; m < 4; ++m)
#pragma unroll
    for (int h = 0; h < 2; ++h)
      afr[m][h] = *(const s16x8*)&E1[(m * 16 + c4) * 64 + h * 32 + q * 8];

  // B fragments from right child E^T, rows scaled by exp(m2-mu)
  const unsigned short* Et2 = inEt + ri;
  s16x8 bfr[2][4];
#pragma unroll
  for (int h = 0; h < 2; ++h) {
    f32x4 s0 = *(const f32x4*)&sS[h * 32 + q * 8];
    f32x4 s1 = *(const f32x4*)&sS[h * 32 + q * 8 + 4];
#pragma unroll
    for (int n = 0; n < 4; ++n) {
      u32x4 raw = *(const u32x4*)&Et2[(n * 16 + c4) * 64 + h * 32 + q * 8];
      unsigned p0 = cvtpk(bflo(raw.x) * s0[0], bfhi(raw.x) * s0[1]);
      unsigned p1 = cvtpk(bflo(raw.y) * s0[2], bfhi(raw.y) * s0[3]);
      unsigned p2 = cvtpk(bflo(raw.z) * s1[0], bfhi(raw.z) * s1[1]);
      unsigned p3 = cvtpk(bflo(raw.w) * s1[2], bfhi(raw.w) * s1[3]);
      u32x4 o; o.x = p0; o.y = p1; o.z = p2; o.w = p3;
      bfr[h][n] = *(s16x8*)&o;
    }
  }

  f32x4 acc[4][4];
#pragma unroll
  for (int m = 0; m < 4; ++m)
#pragma unroll
    for (int n = 0; n < 4; ++n) {
      f32x4 c = {0.f, 0.f, 0.f, 0.f};
      c = __builtin_amdgcn_mfma_f32_16x16x32_bf16(afr[m][0], bfr[0][n], c, 0, 0, 0);
      c = __builtin_amdgcn_mfma_f32_16x16x32_bf16(afr[m][1], bfr[1][n], c, 0, 0, 0);
      acc[m][n] = c;
    }

  const size_t oi = (size_t)(b * outBS + p) * 4096;
  unsigned short* Eo  = outE + oi;
  unsigned short* Eto = outEt + oi;
  float* mo = outM + (size_t)(b * outBS + p) * 64;

#pragma unroll
  for (int m = 0; m < 4; ++m) {
    float rmax[4];
#pragma unroll
    for (int r = 0; r < 4; ++r) {
      float v = fmaxf(fmaxf(acc[m][0][r], acc[m][1][r]),
                      fmaxf(acc[m][2][r], acc[m][3][r]));
      v = fmaxf(v, __shfl_xor(v, 1));
      v = fmaxf(v, __shfl_xor(v, 2));
      v = fmaxf(v, __shfl_xor(v, 4));
      v = fmaxf(v, __shfl_xor(v, 8));
      rmax[r] = v;
    }
    float inv[4] = {__builtin_amdgcn_rcpf(rmax[0]), __builtin_amdgcn_rcpf(rmax[1]),
                    __builtin_amdgcn_rcpf(rmax[2]), __builtin_amdgcn_rcpf(rmax[3])};
#pragma unroll
    for (int n = 0; n < 4; ++n) {
      unsigned p01 = cvtpk(acc[m][n][0] * inv[0], acc[m][n][1] * inv[1]);
      unsigned p23 = cvtpk(acc[m][n][2] * inv[2], acc[m][n][3] * inv[3]);
      unsigned long long packed = (unsigned long long)p01 |
                                  ((unsigned long long)p23 << 32);
      *(unsigned long long*)&Eto[(16 * n + c4) * 64 + 16 * m + 4 * q] = packed;
      Eo[(16 * m + 4 * q + 0) * 64 + 16 * n + c4] = (unsigned short)(p01 & 0xffffu);
      Eo[(16 * m + 4 * q + 1) * 64 + 16 * n + c4] = (unsigned short)(p01 >> 16);
      Eo[(16 * m + 4 * q + 2) * 64 + 16 * n + c4] = (unsigned short)(p23 & 0xffffu);
      Eo[(16 * m + 4 * q + 3) * 64 + 16 * n + c4] = (unsigned short)(p23 >> 16);
    }
    if (c4 == 0) {
#pragma unroll
      for (int r = 0; r < 4; ++r) {
        int i = 16 * m + 4 * q + r;
        mo[i] = sM1[i] + mu + __logf(rmax[r]);
      }
    }
  }
}

// ---------------- Final ----------------

__global__ __launch_bounds__(64)
void hmm_final(const unsigned short* __restrict__ E, const float* __restrict__ M,
               int bs, const float* __restrict__ linit, float* __restrict__ out) {
  const int b = blockIdx.x, l = threadIdx.x;
  const unsigned short* Eb = E + (size_t)b * bs * 4096;
  float av = linit[b * 64 + l] + M[(size_t)b * bs * 64 + l];
  float mx = av;
  mx = fmaxf(mx, __shfl_xor(mx, 1));  mx = fmaxf(mx, __shfl_xor(mx, 2));
  mx = fmaxf(mx, __shfl_xor(mx, 4));  mx = fmaxf(mx, __shfl_xor(mx, 8));
  mx = fmaxf(mx, __shfl_xor(mx, 16)); mx = fmaxf(mx, __shfl_xor(mx, 32));
  float u = __expf(av - mx);
  float rs = 0.f;
#pragma unroll
  for (int e = 0; e < 8; ++e) {
    u32x4 raw = *(const u32x4*)&Eb[l * 64 + e * 8];
    rs += bflo(raw.x) + bfhi(raw.x) + bflo(raw.y) + bfhi(raw.y) +
          bflo(raw.z) + bfhi(raw.z) + bflo(raw.w) + bfhi(raw.w);
  }
  float s = u * rs;
  s += __shfl_xor(s, 1);  s += __shfl_xor(s, 2);  s += __shfl_xor(s, 4);
  s += __shfl_xor(s, 8);  s += __shfl_xor(s, 16); s += __shfl_xor(s, 32);
  if (l == 0) out[b] = mx + __logf(s);
}

extern "C" void kernel_launch(void* const* d_in, const int* in_sizes, int n_in,
                              void* d_out, int out_size, void* d_ws, size_t ws_size,
                              hipStream_t stream) {
  (void)in_sizes; (void)n_in; (void)out_size; (void)ws_size;
  const float* lf    = (const float*)d_in[0];  // [B,T,S,S] fp32
  const float* linit = (const float*)d_in[1];  // [B,S] fp32
  float* out = (float*)d_out;                  // [B] fp32

  // ws layout: A region (1024 matrices), B region (512 matrices)
  unsigned short* E_A  = (unsigned short*)d_ws;
  unsigned short* Et_A = E_A + (size_t)1024 * 4096;
  float*          M_A  = (float*)(Et_A + (size_t)1024 * 4096);
  unsigned short* E_B  = (unsigned short*)(M_A + (size_t)1024 * 64);
  unsigned short* Et_B = E_B + (size_t)512 * 4096;
  float*          M_B  = (float*)(Et_B + (size_t)512 * 4096);

  hmm_phase1<<<dim3(HMM_B * HMM_C), dim3(256), 0, stream>>>(lf, E_A, Et_A, M_A);

  hmm_combine<<<dim3(8 * 64), dim3(64), 0, stream>>>(E_A, Et_A, M_A, 128,
                                                     E_B, Et_B, M_B, 64, 64);
  hmm_combine<<<dim3(8 * 32), dim3(64), 0, stream>>>(E_B, Et_B, M_B, 64,
                                                     E_A, Et_A, M_A, 128, 32);
  hmm_combine<<<dim3(8 * 16), dim3(64), 0, stream>>>(E_A, Et_A, M_A, 128,
                                                     E_B, Et_B, M_B, 64, 16);
  hmm_combine<<<dim3(8 * 8),  dim3(64), 0, stream>>>(E_B, Et_B, M_B, 64,
                                                     E_A, Et_A, M_A, 128, 8);
  hmm_combine<<<dim3(8 * 4),  dim3(64), 0, stream>>>(E_A, Et_A, M_A, 128,
                                                     E_B, Et_B, M_B, 64, 4);
  hmm_combine<<<dim3(8 * 2),  dim3(64), 0, stream>>>(E_B, Et_B, M_B, 64,
                                                     E_A, Et_A, M_A, 128, 2);
  hmm_combine<<<dim3(8 * 1),  dim3(64), 0, stream>>>(E_A, Et_A, M_A, 128,
                                                     E_B, Et_B, M_B, 64, 1);

  hmm_final<<<dim3(HMM_B), dim3(64), 0, stream>>>(E_B, M_B, 64, linit, out);
}